// Round 6
// baseline (288.356 us; speedup 1.0000x reference)
//
#include <hip/hip_runtime.h>

#define BB 8
#define CC 64
#define HH 128
#define WW 128
#define TT 3
#define LL 4
#define MM 3

#define PW 130                         // padded spatial dim
#define CHP ((size_t)PW * PW * 16)     // halves per 16-ch chunk plane
#define IMGH ((size_t)PW * PW * CC)    // halves per padded image (= 4*CHP)

typedef _Float16 half8 __attribute__((ext_vector_type(8)));
typedef _Float16 half4 __attribute__((ext_vector_type(4)));
typedef float floatx16 __attribute__((ext_vector_type(16)));

__device__ __forceinline__ void async_ld16(const _Float16* g, _Float16* l) {
    __builtin_amdgcn_global_load_lds(
        (const __attribute__((address_space(1))) void*)g,
        (__attribute__((address_space(3))) void*)l, 16, 0, 0);
}

// ---------------------------------------------------------------------------
// Weight prep (+ inline routing): every block recomputes the argmax chain,
// gathers the selected module, fp32 -> fp16, A-frag order:
// W3[tl][tap][c(2)][il(2)][o(2)][lane(64)*8] -- one a-frag = contiguous 1 KB.
// ---------------------------------------------------------------------------
__global__ __launch_bounds__(256) void prep_weights(
    const float* __restrict__ enc_w, // [L][M][64][64][3][3]
    const float* __restrict__ alpha0,
    const float* __restrict__ alphas,
    const float* __restrict__ g0,
    const float* __restrict__ gs,
    int* __restrict__ sel,           // [T][L]
    _Float16* __restrict__ W3)       // [12][36864]
{
    int tl = blockIdx.y;
    int t = tl >> 2, layer = tl & 3;
    int idx = 0;
    for (int l = 0; l <= layer; ++l) {
        const float *a, *g;
        if (l == 0) { a = alpha0 + t * MM; g = g0 + t * MM; }
        else {
            int off = (((l - 1) * TT + t) * MM + idx) * MM;
            a = alphas + off; g = gs + off;
        }
        float best = a[0] + g[0];
        int bi = 0;
        for (int j = 1; j < MM; ++j) {
            float v = a[j] + g[j];
            if (v > best) { best = v; bi = j; }
        }
        idx = bi;
    }
    const int m = idx;
    if (blockIdx.x == 0 && threadIdx.x == 0) sel[tl] = m;

    const float* src = enc_w + ((size_t)layer * MM + m) * (CC * CC * 9);
    _Float16* dst = W3 + (size_t)tl * 36864;
    for (int i = blockIdx.x * 256 + threadIdx.x; i < 36864; i += gridDim.x * 256) {
        int j   = i & 7;
        int l   = (i >> 3) & 63;
        int o   = (i >> 9) & 1;
        int il  = (i >> 10) & 1;
        int c   = (i >> 11) & 1;
        int tap = i >> 12;                      // 0..8
        int oc  = o * 32 + (l & 31);
        int kch = c * 32 + il * 16 + (l >> 5) * 8 + j;
        dst[i] = (_Float16)src[(oc * CC + kch) * 9 + tap];
    }
}

// ---------------------------------------------------------------------------
// Zero the 1-px borders of chunk-plane padded images.
// ---------------------------------------------------------------------------
__global__ __launch_bounds__(256) void zero_borders(_Float16* __restrict__ base0)
{
    _Float16* base = base0 + (size_t)blockIdx.x * IMGH;
    const int i0 = blockIdx.y * 1032;
    for (int i = i0 + threadIdx.x; i < i0 + 1032; i += 256) {
        // 4128 half8 items: plane(4) x 516 border px x 2
        int pl  = i / 1032;
        int rem = i - pl * 1032;
        int px_idx = rem >> 1, sh = rem & 1;
        int row, col;
        if (px_idx < 130)      { row = 0;            col = px_idx; }
        else if (px_idx < 260) { row = 129;          col = px_idx - 130; }
        else if (px_idx < 388) { row = px_idx - 259; col = 0; }
        else                   { row = px_idx - 387; col = 129; }
        half8 z = {};
        *(half8*)(base + (size_t)pl * CHP + ((size_t)row * PW + col) * 16 + sh * 8) = z;
    }
}

// ---------------------------------------------------------------------------
// x: NCHW fp32 -> chunk-plane padded f16: [B][4][130*130][16] (interior).
// ---------------------------------------------------------------------------
__global__ __launch_bounds__(256) void to_chunked(
    const float* __restrict__ x,    // [B][64][128][128]
    _Float16* __restrict__ act0)
{
    const int xs = blockIdx.x;  // 0..1
    const int y  = blockIdx.y;  // 0..127
    const int b  = blockIdx.z;  // 0..7

    __shared__ _Float16 lds[64 * 72];  // [px][ch], pad 72

    const int wv = threadIdx.x >> 6;
    const int l  = threadIdx.x & 63;
    const float* src = x + ((size_t)b * CC * HH + y) * WW + xs * 64 + l;
#pragma unroll
    for (int k = 0; k < 16; ++k) {
        int ch = wv * 16 + k;
        lds[l * 72 + ch] = (_Float16)src[(size_t)ch * HH * WW];
    }
    __syncthreads();
    int px = threadIdx.x & 63;
    int q  = threadIdx.x >> 6;      // plane
    _Float16* dst = act0 + (size_t)b * IMGH + (size_t)q * CHP
                  + ((size_t)(y + 1) * PW + xs * 64 + px + 1) * 16;
    *(half8*)dst       = *(const half8*)&lds[px * 72 + q * 16];
    *(half8*)(dst + 8) = *(const half8*)&lds[px * 72 + q * 16 + 8];
}

// ---------------------------------------------------------------------------
// 3x3 SAME conv + bias + ReLU, chunk-plane f16 layout, MFMA 32x32x16.
// Grid 32x8 (ONE task): 1 block/CU, no grid tail; chunked XCD swizzle maps
// batch b -> XCD b each launch, so layer k+1 reads layer k's output from
// that XCD's L2 (2.2MB in + 2.2MB out < 4MB).
// Counted-vmcnt pipeline (T4): every wave issues exactly 10 DMA ops per
// phase; s_waitcnt vmcnt(10) + raw s_barrier keeps the next phase's loads
// in flight across barriers (no drain-to-zero bubbles).
// ---------------------------------------------------------------------------
__global__ __launch_bounds__(256, 2) void conv3x3_mfma(
    const _Float16* __restrict__ in,   // chunked padded (one task)
    _Float16* __restrict__ out,        // chunked padded (one task)
    const _Float16* __restrict__ W3,   // [12][36864]
    const float* __restrict__ enc_b,   // [L][M][64]
    const int* __restrict__ sel,
    int layer, int task0, size_t tsi, size_t tso)
{
    // ---- bijective chunked XCD swizzle over the flattened grid ----
    const int nwg  = gridDim.x * gridDim.y * gridDim.z;   // 256
    const int flat = blockIdx.x + gridDim.x * (blockIdx.y + gridDim.y * blockIdx.z);
    const int q8   = nwg >> 3;
    const int logical = (flat & 7) * q8 + (flat >> 3);
    const int bx  = logical & 31;          // gridDim.x == 32
    const int rem = logical >> 5;
    const int b   = rem & 7;               // gridDim.y == 8
    const int tz  = rem >> 3;              // 0

    const int y0  = (bx >> 1) * 8;   // padded row of halo top
    const int px0 = (bx & 1) * 64;   // padded col of halo left
    const int t   = task0 + tz;

    const _Float16* inp = in + (size_t)tz * tsi + (size_t)b * IMGH;
    _Float16* outp      = out + (size_t)tz * tso + (size_t)b * IMGH;
    const int tl = t * LL + layer;
    const _Float16* Wt = W3 + (size_t)tl * 36864;

    const int tid  = threadIdx.x;
    const int lane = tid & 63;
    const int w    = tid >> 6;        // wave id; rows 2w, 2w+1 of the 8
    const int n    = lane & 31;
    const int ksub = lane >> 5;

    // act buf: 21 slots x 512 halves = 10752 halves (21504B) each
    // wt buf : 18 frags x 512 halves =  9216 halves (18432B) each
    __shared__ __align__(16) _Float16 lds[2 * 10752 + 2 * 9216];
    _Float16* actb0 = lds;
    _Float16* actb1 = lds + 10752;
    _Float16* wtb0  = lds + 21504;
    _Float16* wtb1  = lds + 21504 + 9216;

    floatx16 acc[2][2][2];   // [rr][o][j]
#pragma unroll
    for (int rr = 0; rr < 2; ++rr)
#pragma unroll
        for (int o = 0; o < 2; ++o)
#pragma unroll
            for (int j = 0; j < 2; ++j)
#pragma unroll
                for (int i = 0; i < 16; ++i) acc[rr][o][j][i] = 0.f;

    // b-frag read offsets (halves) per [dx][h]
    int preoff[3][2];
#pragma unroll
    for (int dx = 0; dx < 3; ++dx)
#pragma unroll
        for (int h = 0; h < 2; ++h) {
            int pxv = dx + n + 32 * h;
            preoff[dx][h] = pxv * 16 + ((ksub ^ ((pxv >> 2) & 1)) << 3);
        }

    // ---- stage one plane-phase: EXACTLY 10 DMA ops per wave ----
    // op q = w + 4k, k=0..9; q<21 -> act slot q; else wt slot min(q-21,17)
#define STAGE(p, actd, wtd)                                                    \
    {                                                                          \
        const _Float16* plane = inp + (size_t)(p) * CHP;                       \
        const int c_ = (p) >> 1, il_ = (p) & 1;                                \
        _Pragma("unroll")                                                      \
        for (int k10 = 0; k10 < 10; ++k10) {                                   \
            int q = w + 4 * k10;              /* wave-uniform */               \
            if (q < 21) {                                                      \
                int si = q * 64 + lane;       /* 16B slot 0..1343 */           \
                int s16 = si & 1;                                              \
                int u = si >> 1;              /* px-slot */                    \
                if (u > 659) u = 659;         /* tail dups -> clamp */         \
                int r = (u * 993) >> 16;      /* u/66, exact for u<660 */      \
                int px = u - r * 66;                                           \
                const _Float16* src =                                          \
                    plane + ((size_t)(y0 + r) * PW + (px0 + px)) * 16          \
                          + ((s16 ^ ((px >> 2) & 1)) << 3);                    \
                async_ld16(src, (actd) + q * 512);                             \
            } else {                                                           \
                int k = q - 21; if (k > 17) k = 17;  /* one benign dup */      \
                const _Float16* src =                                          \
                    Wt + ((k >> 1) * 8 + c_ * 4 + il_ * 2 + (k & 1)) * 512     \
                       + lane * 8;                                             \
                async_ld16(src, (wtd) + k * 512);                              \
            }                                                                  \
        }                                                                      \
    }

#define COMPUTE(al, wl)                                                        \
    {                                                                          \
        __builtin_amdgcn_s_setprio(1);                                         \
        _Pragma("unroll")                                                      \
        for (int tap = 0; tap < 9; ++tap) {                                    \
            const int dy = tap / 3;                                            \
            const int dx = tap - dy * 3;                                       \
            half8 a0 = *(const half8*)((wl) + (tap * 2 + 0) * 512 + lane * 8); \
            half8 a1 = *(const half8*)((wl) + (tap * 2 + 1) * 512 + lane * 8); \
            _Pragma("unroll")                                                  \
            for (int rr = 0; rr < 2; ++rr) {                                   \
                const _Float16* lb = (al) + (2 * w + rr + dy) * 1056;          \
                half8 b0 = *(const half8*)(lb + preoff[dx][0]);                \
                half8 b1 = *(const half8*)(lb + preoff[dx][1]);                \
                acc[rr][0][0] = __builtin_amdgcn_mfma_f32_32x32x16_f16(a0, b0, acc[rr][0][0], 0, 0, 0); \
                acc[rr][0][1] = __builtin_amdgcn_mfma_f32_32x32x16_f16(a0, b1, acc[rr][0][1], 0, 0, 0); \
                acc[rr][1][0] = __builtin_amdgcn_mfma_f32_32x32x16_f16(a1, b0, acc[rr][1][0], 0, 0, 0); \
                acc[rr][1][1] = __builtin_amdgcn_mfma_f32_32x32x16_f16(a1, b1, acc[rr][1][1], 0, 0, 0); \
            }                                                                  \
        }                                                                      \
        __builtin_amdgcn_s_setprio(0);                                         \
    }

#define WAITN(nlit)                                                            \
    asm volatile("s_waitcnt vmcnt(" #nlit ")" ::: "memory");                   \
    __builtin_amdgcn_sched_barrier(0)
#define BAR()                                                                  \
    __builtin_amdgcn_sched_barrier(0);                                         \
    __builtin_amdgcn_s_barrier();                                              \
    __builtin_amdgcn_sched_barrier(0)

    STAGE(0, actb0, wtb0);                 // 10 ops in flight
    STAGE(1, actb1, wtb1);                 // 20 in flight
    WAITN(10); BAR();                      // phase0 landed; phase1 in flight
    COMPUTE(actb0, wtb0);
    BAR();                                 // all reads of buf0 done
    STAGE(2, actb0, wtb0);
    WAITN(10); BAR();                      // phase1 landed; phase2 in flight
    COMPUTE(actb1, wtb1);
    BAR();                                 // all reads of buf1 done
    STAGE(3, actb1, wtb1);
    WAITN(10); BAR();                      // phase2 landed; phase3 in flight
    COMPUTE(actb0, wtb0);
    WAITN(0); BAR();                       // phase3 landed
    COMPUTE(actb1, wtb1);
#undef STAGE
#undef COMPUTE
#undef WAITN
#undef BAR

    // ---- epilogue: bias + ReLU -> chunk-plane f16 interior ----
    int m = sel[t * LL + layer];
    m = __builtin_amdgcn_readfirstlane(m);
    const float* Bp = enc_b + ((size_t)layer * MM + m) * CC;
#pragma unroll
    for (int rr = 0; rr < 2; ++rr) {
#pragma unroll
        for (int o = 0; o < 2; ++o)
#pragma unroll
            for (int j = 0; j < 2; ++j) {
                int px = px0 + j * 32 + n;
                size_t pxi = (size_t)(y0 + 2 * w + rr + 1) * PW + px + 1;
#pragma unroll
                for (int rg = 0; rg < 4; ++rg) {
                    int oci = 4 * ksub + 8 * rg;          // 0..28
                    int pl  = o * 2 + (oci >> 4);
                    _Float16* po = outp + (size_t)pl * CHP + pxi * 16 + (oci & 15);
                    half4 h;
#pragma unroll
                    for (int k = 0; k < 4; ++k)
                        h[k] = (_Float16)fmaxf(acc[rr][o][j][rg * 4 + k]
                                               + Bp[o * 32 + oci + k], 0.f);
                    *(half4*)po = h;
                }
            }
    }
}

// ---------------------------------------------------------------------------
// Decoder: 1x1 conv 64 -> 3 (+bias), L2-normalize task 2. Chunk-plane input.
// ---------------------------------------------------------------------------
__global__ __launch_bounds__(256) void decoder_kernel(
    const _Float16* __restrict__ in, // chunked padded, per-task stride ts halves
    size_t ts,
    const float* __restrict__ dec_w, // [T][3][64]
    const float* __restrict__ dec_b, // [T][3]
    float* __restrict__ out,         // [T][B][3][H][W]
    int task0, int ntask)
{
    const int HW = HH * WW;
    int gid = blockIdx.x * 256 + threadIdx.x;
    if (gid >= ntask * BB * HW) return;
    int tz = gid / (BB * HW);
    int rem = gid - tz * (BB * HW);
    int b = rem / HW;
    int px = rem - b * HW;
    int t = task0 + tz;
    int y = px >> 7;
    int xx = px & 127;

    const _Float16* base = in + (size_t)tz * ts + (size_t)b * IMGH;
    size_t pxi = ((size_t)(y + 1) * PW + xx + 1) * 16;
    const float* w = dec_w + (size_t)t * 3 * CC;

    float a0 = dec_b[t * 3 + 0];
    float a1 = dec_b[t * 3 + 1];
    float a2 = dec_b[t * 3 + 2];
#pragma unroll
    for (int il = 0; il < 4; ++il) {
        const _Float16* hp = base + (size_t)il * CHP + pxi;
#pragma unroll
        for (int cc = 0; cc < 16; cc += 8) {
            half8 h = *(const half8*)(hp + cc);
#pragma unroll
            for (int k = 0; k < 8; ++k) {
                float v = (float)h[k];
                int ch = il * 16 + cc + k;
                a0 += v * w[ch];
                a1 += v * w[CC + ch];
                a2 += v * w[2 * CC + ch];
            }
        }
    }
    if (t == 2) {
        float r = 1.0f / sqrtf(a0 * a0 + a1 * a1 + a2 * a2);
        a0 *= r; a1 *= r; a2 *= r;
    }
    float* ob = out + ((size_t)t * BB + b) * 3 * HW + px;
    ob[0]      = a0;
    ob[HW]     = a1;
    ob[2 * HW] = a2;
}

extern "C" void kernel_launch(void* const* d_in, const int* in_sizes, int n_in,
                              void* d_out, int out_size, void* d_ws, size_t ws_size,
                              hipStream_t stream) {
    const float* x      = (const float*)d_in[0];
    const float* alpha0 = (const float*)d_in[1];
    const float* alphas = (const float*)d_in[2];
    const float* g0     = (const float*)d_in[3];
    const float* gs     = (const float*)d_in[4];
    const float* enc_w  = (const float*)d_in[5];
    const float* enc_b  = (const float*)d_in[6];
    const float* dec_w  = (const float*)d_in[7];
    const float* dec_b  = (const float*)d_in[8];
    float* out = (float*)d_out;

    const size_t ACT = (size_t)BB * IMGH;      // halves per padded activation buffer
    char* pw = (char*)d_ws;
    int* sel = (int*)pw;                 pw += 1024;
    _Float16* W3 = (_Float16*)pw;        pw += (size_t)12 * 36864 * 2;
    _Float16* act0 = (_Float16*)pw;      pw += ACT * 2;
    _Float16* A = (_Float16*)pw;         pw += ACT * 2;
    _Float16* B = (_Float16*)pw;

    prep_weights<<<dim3(36, 12), 256, 0, stream>>>(enc_w, alpha0, alphas, g0, gs, sel, W3);
    zero_borders<<<dim3(3 * BB, 4), 256, 0, stream>>>(act0);   // act0, A, B contiguous
    to_chunked<<<dim3(2, HH, BB), 256, 0, stream>>>(x, act0);

    // Per-task sequential chains: 256-block grids (1 block/CU, no tail);
    // stable tile->XCD mapping across launches gives inter-layer L2 reuse.
    for (int t = 0; t < TT; ++t) {
        conv3x3_mfma<<<dim3(32, BB, 1), 256, 0, stream>>>(act0, A, W3, enc_b, sel, 0, t, 0, 0);
        conv3x3_mfma<<<dim3(32, BB, 1), 256, 0, stream>>>(A,    B, W3, enc_b, sel, 1, t, 0, 0);
        conv3x3_mfma<<<dim3(32, BB, 1), 256, 0, stream>>>(B,    A, W3, enc_b, sel, 2, t, 0, 0);
        conv3x3_mfma<<<dim3(32, BB, 1), 256, 0, stream>>>(A,    B, W3, enc_b, sel, 3, t, 0, 0);
        decoder_kernel<<<(BB * HH * WW + 255) / 256, 256, 0, stream>>>(
            B, 0, dec_w, dec_b, out, t, 1);
    }
}

// Round 7
// 249.858 us; speedup vs baseline: 1.1541x; 1.1541x over previous
//
#include <hip/hip_runtime.h>

#define BB 8
#define CC 64
#define HH 128
#define WW 128
#define TT 3
#define LL 4
#define MM 3

#define PW 130                         // padded spatial dim
#define CHP ((size_t)PW * PW * 16)     // halves per 16-ch chunk plane
#define IMGH ((size_t)PW * PW * CC)    // halves per padded image (= 4*CHP)

typedef _Float16 half8 __attribute__((ext_vector_type(8)));
typedef _Float16 half4 __attribute__((ext_vector_type(4)));
typedef float floatx16 __attribute__((ext_vector_type(16)));

__device__ __forceinline__ void async_ld16(const _Float16* g, _Float16* l) {
    __builtin_amdgcn_global_load_lds(
        (const __attribute__((address_space(1))) void*)g,
        (__attribute__((address_space(3))) void*)l, 16, 0, 0);
}

// ---------------------------------------------------------------------------
// Weight prep (+ inline routing): every block recomputes the argmax chain,
// gathers the selected module, fp32 -> fp16, A-frag order:
// W3[tl][tap][c(2)][il(2)][o(2)][lane(64)*8] -- one a-frag = contiguous 1 KB.
// ---------------------------------------------------------------------------
__global__ __launch_bounds__(256) void prep_weights(
    const float* __restrict__ enc_w, // [L][M][64][64][3][3]
    const float* __restrict__ alpha0,
    const float* __restrict__ alphas,
    const float* __restrict__ g0,
    const float* __restrict__ gs,
    int* __restrict__ sel,           // [T][L]
    _Float16* __restrict__ W3)       // [12][36864]
{
    int tl = blockIdx.y;
    int t = tl >> 2, layer = tl & 3;
    int idx = 0;
    for (int l = 0; l <= layer; ++l) {
        const float *a, *g;
        if (l == 0) { a = alpha0 + t * MM; g = g0 + t * MM; }
        else {
            int off = (((l - 1) * TT + t) * MM + idx) * MM;
            a = alphas + off; g = gs + off;
        }
        float best = a[0] + g[0];
        int bi = 0;
        for (int j = 1; j < MM; ++j) {
            float v = a[j] + g[j];
            if (v > best) { best = v; bi = j; }
        }
        idx = bi;
    }
    const int m = idx;
    if (blockIdx.x == 0 && threadIdx.x == 0) sel[tl] = m;

    const float* src = enc_w + ((size_t)layer * MM + m) * (CC * CC * 9);
    _Float16* dst = W3 + (size_t)tl * 36864;
    for (int i = blockIdx.x * 256 + threadIdx.x; i < 36864; i += gridDim.x * 256) {
        int j   = i & 7;
        int l   = (i >> 3) & 63;
        int o   = (i >> 9) & 1;
        int il  = (i >> 10) & 1;
        int c   = (i >> 11) & 1;
        int tap = i >> 12;                      // 0..8
        int oc  = o * 32 + (l & 31);
        int kch = c * 32 + il * 16 + (l >> 5) * 8 + j;
        dst[i] = (_Float16)src[(oc * CC + kch) * 9 + tap];
    }
}

// ---------------------------------------------------------------------------
// Zero the 1-px borders of chunk-plane padded images.
// ---------------------------------------------------------------------------
__global__ __launch_bounds__(256) void zero_borders(_Float16* __restrict__ base0)
{
    _Float16* base = base0 + (size_t)blockIdx.x * IMGH;
    const int i0 = blockIdx.y * 1032;
    for (int i = i0 + threadIdx.x; i < i0 + 1032; i += 256) {
        // 4128 half8 items: plane(4) x 516 border px x 2
        int pl  = i / 1032;
        int rem = i - pl * 1032;
        int px_idx = rem >> 1, sh = rem & 1;
        int row, col;
        if (px_idx < 130)      { row = 0;            col = px_idx; }
        else if (px_idx < 260) { row = 129;          col = px_idx - 130; }
        else if (px_idx < 388) { row = px_idx - 259; col = 0; }
        else                   { row = px_idx - 387; col = 129; }
        half8 z = {};
        *(half8*)(base + (size_t)pl * CHP + ((size_t)row * PW + col) * 16 + sh * 8) = z;
    }
}

// ---------------------------------------------------------------------------
// x: NCHW fp32 -> chunk-plane padded f16: [B][4][130*130][16] (interior).
// ---------------------------------------------------------------------------
__global__ __launch_bounds__(256) void to_chunked(
    const float* __restrict__ x,    // [B][64][128][128]
    _Float16* __restrict__ act0)
{
    const int xs = blockIdx.x;  // 0..1
    const int y  = blockIdx.y;  // 0..127
    const int b  = blockIdx.z;  // 0..7

    __shared__ _Float16 lds[64 * 72];  // [px][ch], pad 72

    const int wv = threadIdx.x >> 6;
    const int l  = threadIdx.x & 63;
    const float* src = x + ((size_t)b * CC * HH + y) * WW + xs * 64 + l;
#pragma unroll
    for (int k = 0; k < 16; ++k) {
        int ch = wv * 16 + k;
        lds[l * 72 + ch] = (_Float16)src[(size_t)ch * HH * WW];
    }
    __syncthreads();
    int px = threadIdx.x & 63;
    int q  = threadIdx.x >> 6;      // plane
    _Float16* dst = act0 + (size_t)b * IMGH + (size_t)q * CHP
                  + ((size_t)(y + 1) * PW + xs * 64 + px + 1) * 16;
    *(half8*)dst       = *(const half8*)&lds[px * 72 + q * 16];
    *(half8*)(dst + 8) = *(const half8*)&lds[px * 72 + q * 16 + 8];
}

// ---------------------------------------------------------------------------
// 3x3 SAME conv + bias + ReLU, chunk-plane f16 layout, MFMA 32x32x16.
// Fused grid 32x8x3 (768 blocks, 2/CU).  K split into 4 phases of 16 ch =
// one chunk PLANE each (clean line consumption, r5-verified).  Counted-
// vmcnt pipeline (T4): every wave issues exactly 10 DMA ops per phase;
// s_waitcnt vmcnt(10) + raw s_barrier keeps the next phase's loads in
// flight across barriers (no drain-to-zero bubble at phase boundaries).
// LDS 79,872 B.  Bijective chunked XCD swizzle for L2 locality.
// ---------------------------------------------------------------------------
__global__ __launch_bounds__(256, 2) void conv3x3_mfma(
    const _Float16* __restrict__ in,   // chunked padded, per task stride tsi
    _Float16* __restrict__ out,        // chunked padded, per task stride tso
    const _Float16* __restrict__ W3,   // [12][36864]
    const float* __restrict__ enc_b,   // [L][M][64]
    const int* __restrict__ sel,
    int layer, int task0, size_t tsi, size_t tso)
{
    // ---- bijective chunked XCD swizzle over the flattened grid ----
    const int nwg  = gridDim.x * gridDim.y * gridDim.z;   // 768 (fused) / 256
    const int flat = blockIdx.x + gridDim.x * (blockIdx.y + gridDim.y * blockIdx.z);
    const int q8   = nwg >> 3;
    const int logical = (flat & 7) * q8 + (flat >> 3);
    const int bx  = logical & 31;          // gridDim.x == 32
    const int rem = logical >> 5;
    const int b   = rem & 7;               // gridDim.y == 8
    const int tz  = rem >> 3;

    const int y0  = (bx >> 1) * 8;   // padded row of halo top
    const int px0 = (bx & 1) * 64;   // padded col of halo left
    const int t   = task0 + tz;

    const _Float16* inp = in + (size_t)tz * tsi + (size_t)b * IMGH;
    _Float16* outp      = out + (size_t)tz * tso + (size_t)b * IMGH;
    const int tl = t * LL + layer;
    const _Float16* Wt = W3 + (size_t)tl * 36864;

    const int tid  = threadIdx.x;
    const int lane = tid & 63;
    const int w    = tid >> 6;        // wave id; rows 2w, 2w+1 of the 8
    const int n    = lane & 31;
    const int ksub = lane >> 5;

    // act buf: 21 slots x 512 halves = 10752 halves (21504B) each
    // wt buf : 18 frags x 512 halves =  9216 halves (18432B) each
    __shared__ __align__(16) _Float16 lds[2 * 10752 + 2 * 9216];
    _Float16* actb0 = lds;
    _Float16* actb1 = lds + 10752;
    _Float16* wtb0  = lds + 21504;
    _Float16* wtb1  = lds + 21504 + 9216;

    floatx16 acc[2][2][2];   // [rr][o][j]
#pragma unroll
    for (int rr = 0; rr < 2; ++rr)
#pragma unroll
        for (int o = 0; o < 2; ++o)
#pragma unroll
            for (int j = 0; j < 2; ++j)
#pragma unroll
                for (int i = 0; i < 16; ++i) acc[rr][o][j][i] = 0.f;

    // b-frag read offsets (halves) per [dx][h]
    int preoff[3][2];
#pragma unroll
    for (int dx = 0; dx < 3; ++dx)
#pragma unroll
        for (int h = 0; h < 2; ++h) {
            int pxv = dx + n + 32 * h;
            preoff[dx][h] = pxv * 16 + ((ksub ^ ((pxv >> 2) & 1)) << 3);
        }

    // ---- stage one plane-phase: EXACTLY 10 DMA ops per wave ----
    // op q = w + 4k, k=0..9; q<21 -> act slot q; else wt slot min(q-21,17)
#define STAGE(p, actd, wtd)                                                    \
    {                                                                          \
        const _Float16* plane = inp + (size_t)(p) * CHP;                       \
        const int c_ = (p) >> 1, il_ = (p) & 1;                                \
        _Pragma("unroll")                                                      \
        for (int k10 = 0; k10 < 10; ++k10) {                                   \
            int q = w + 4 * k10;              /* wave-uniform */               \
            if (q < 21) {                                                      \
                int si = q * 64 + lane;       /* 16B slot 0..1343 */           \
                int s16 = si & 1;                                              \
                int u = si >> 1;              /* px-slot */                    \
                if (u > 659) u = 659;         /* tail dups -> clamp */         \
                int r = (u * 993) >> 16;      /* u/66, exact for u<660 */      \
                int px = u - r * 66;                                           \
                const _Float16* src =                                          \
                    plane + ((size_t)(y0 + r) * PW + (px0 + px)) * 16          \
                          + ((s16 ^ ((px >> 2) & 1)) << 3);                    \
                async_ld16(src, (actd) + q * 512);                             \
            } else {                                                           \
                int k = q - 21; if (k > 17) k = 17;  /* one benign dup */      \
                const _Float16* src =                                          \
                    Wt + ((k >> 1) * 8 + c_ * 4 + il_ * 2 + (k & 1)) * 512     \
                       + lane * 8;                                             \
                async_ld16(src, (wtd) + k * 512);                              \
            }                                                                  \
        }                                                                      \
    }

#define COMPUTE(al, wl)                                                        \
    {                                                                          \
        __builtin_amdgcn_s_setprio(1);                                         \
        _Pragma("unroll")                                                      \
        for (int tap = 0; tap < 9; ++tap) {                                    \
            const int dy = tap / 3;                                            \
            const int dx = tap - dy * 3;                                       \
            half8 a0 = *(const half8*)((wl) + (tap * 2 + 0) * 512 + lane * 8); \
            half8 a1 = *(const half8*)((wl) + (tap * 2 + 1) * 512 + lane * 8); \
            _Pragma("unroll")                                                  \
            for (int rr = 0; rr < 2; ++rr) {                                   \
                const _Float16* lb = (al) + (2 * w + rr + dy) * 1056;          \
                half8 b0 = *(const half8*)(lb + preoff[dx][0]);                \
                half8 b1 = *(const half8*)(lb + preoff[dx][1]);                \
                acc[rr][0][0] = __builtin_amdgcn_mfma_f32_32x32x16_f16(a0, b0, acc[rr][0][0], 0, 0, 0); \
                acc[rr][0][1] = __builtin_amdgcn_mfma_f32_32x32x16_f16(a0, b1, acc[rr][0][1], 0, 0, 0); \
                acc[rr][1][0] = __builtin_amdgcn_mfma_f32_32x32x16_f16(a1, b0, acc[rr][1][0], 0, 0, 0); \
                acc[rr][1][1] = __builtin_amdgcn_mfma_f32_32x32x16_f16(a1, b1, acc[rr][1][1], 0, 0, 0); \
            }                                                                  \
        }                                                                      \
        __builtin_amdgcn_s_setprio(0);                                         \
    }

#define WAITN(nlit)                                                            \
    asm volatile("s_waitcnt vmcnt(" #nlit ")" ::: "memory");                   \
    __builtin_amdgcn_sched_barrier(0)
#define BAR()                                                                  \
    __builtin_amdgcn_sched_barrier(0);                                         \
    __builtin_amdgcn_s_barrier();                                              \
    __builtin_amdgcn_sched_barrier(0)

    STAGE(0, actb0, wtb0);                 // 10 ops in flight
    STAGE(1, actb1, wtb1);                 // 20 in flight
    WAITN(10); BAR();                      // phase0 landed; phase1 in flight
    COMPUTE(actb0, wtb0);
    BAR();                                 // all reads of buf0 done
    STAGE(2, actb0, wtb0);
    WAITN(10); BAR();                      // phase1 landed; phase2 in flight
    COMPUTE(actb1, wtb1);
    BAR();                                 // all reads of buf1 done
    STAGE(3, actb1, wtb1);
    WAITN(10); BAR();                      // phase2 landed; phase3 in flight
    COMPUTE(actb0, wtb0);
    WAITN(0); BAR();                       // phase3 landed
    COMPUTE(actb1, wtb1);
#undef STAGE
#undef COMPUTE
#undef WAITN
#undef BAR

    // ---- epilogue: bias + ReLU -> chunk-plane f16 interior ----
    int m = sel[t * LL + layer];
    m = __builtin_amdgcn_readfirstlane(m);
    const float* Bp = enc_b + ((size_t)layer * MM + m) * CC;
#pragma unroll
    for (int rr = 0; rr < 2; ++rr) {
#pragma unroll
        for (int o = 0; o < 2; ++o)
#pragma unroll
            for (int j = 0; j < 2; ++j) {
                int px = px0 + j * 32 + n;
                size_t pxi = (size_t)(y0 + 2 * w + rr + 1) * PW + px + 1;
#pragma unroll
                for (int rg = 0; rg < 4; ++rg) {
                    int oci = 4 * ksub + 8 * rg;          // 0..28
                    int pl  = o * 2 + (oci >> 4);
                    _Float16* po = outp + (size_t)pl * CHP + pxi * 16 + (oci & 15);
                    half4 h;
#pragma unroll
                    for (int k = 0; k < 4; ++k)
                        h[k] = (_Float16)fmaxf(acc[rr][o][j][rg * 4 + k]
                                               + Bp[o * 32 + oci + k], 0.f);
                    *(half4*)po = h;
                }
            }
    }
}

// ---------------------------------------------------------------------------
// Decoder: 1x1 conv 64 -> 3 (+bias), L2-normalize task 2. Chunk-plane input.
// ---------------------------------------------------------------------------
__global__ __launch_bounds__(256) void decoder_kernel(
    const _Float16* __restrict__ in, // chunked padded, per-task stride ts halves
    size_t ts,
    const float* __restrict__ dec_w, // [T][3][64]
    const float* __restrict__ dec_b, // [T][3]
    float* __restrict__ out,         // [T][B][3][H][W]
    int task0, int ntask)
{
    const int HW = HH * WW;
    int gid = blockIdx.x * 256 + threadIdx.x;
    if (gid >= ntask * BB * HW) return;
    int tz = gid / (BB * HW);
    int rem = gid - tz * (BB * HW);
    int b = rem / HW;
    int px = rem - b * HW;
    int t = task0 + tz;
    int y = px >> 7;
    int xx = px & 127;

    const _Float16* base = in + (size_t)tz * ts + (size_t)b * IMGH;
    size_t pxi = ((size_t)(y + 1) * PW + xx + 1) * 16;
    const float* w = dec_w + (size_t)t * 3 * CC;

    float a0 = dec_b[t * 3 + 0];
    float a1 = dec_b[t * 3 + 1];
    float a2 = dec_b[t * 3 + 2];
#pragma unroll
    for (int il = 0; il < 4; ++il) {
        const _Float16* hp = base + (size_t)il * CHP + pxi;
#pragma unroll
        for (int cc = 0; cc < 16; cc += 8) {
            half8 h = *(const half8*)(hp + cc);
#pragma unroll
            for (int k = 0; k < 8; ++k) {
                float v = (float)h[k];
                int ch = il * 16 + cc + k;
                a0 += v * w[ch];
                a1 += v * w[CC + ch];
                a2 += v * w[2 * CC + ch];
            }
        }
    }
    if (t == 2) {
        float r = 1.0f / sqrtf(a0 * a0 + a1 * a1 + a2 * a2);
        a0 *= r; a1 *= r; a2 *= r;
    }
    float* ob = out + ((size_t)t * BB + b) * 3 * HW + px;
    ob[0]      = a0;
    ob[HW]     = a1;
    ob[2 * HW] = a2;
}

extern "C" void kernel_launch(void* const* d_in, const int* in_sizes, int n_in,
                              void* d_out, int out_size, void* d_ws, size_t ws_size,
                              hipStream_t stream) {
    const float* x      = (const float*)d_in[0];
    const float* alpha0 = (const float*)d_in[1];
    const float* alphas = (const float*)d_in[2];
    const float* g0     = (const float*)d_in[3];
    const float* gs     = (const float*)d_in[4];
    const float* enc_w  = (const float*)d_in[5];
    const float* enc_b  = (const float*)d_in[6];
    const float* dec_w  = (const float*)d_in[7];
    const float* dec_b  = (const float*)d_in[8];
    float* out = (float*)d_out;

    const size_t ACT = (size_t)BB * IMGH;      // halves per padded activation buffer
    char* pw = (char*)d_ws;
    int* sel = (int*)pw;                 pw += 1024;
    _Float16* W3 = (_Float16*)pw;        pw += (size_t)12 * 36864 * 2;
    _Float16* act0 = (_Float16*)pw;      pw += ACT * 2;
    _Float16* bufs = (_Float16*)pw;
    size_t base = (size_t)(pw - (char*)d_ws);
    bool fused = ws_size >= base + 6 * ACT * 2;

    prep_weights<<<dim3(36, 12), 256, 0, stream>>>(enc_w, alpha0, alphas, g0, gs, sel, W3);
    int nbuf = fused ? 7 : 3;
    zero_borders<<<dim3(nbuf * BB, 4), 256, 0, stream>>>(act0);
    to_chunked<<<dim3(2, HH, BB), 256, 0, stream>>>(x, act0);

    if (fused) {
        _Float16* A = bufs;        // task stride 2*ACT
        _Float16* B = bufs + ACT;  // task stride 2*ACT
        size_t ts = 2 * ACT;
        conv3x3_mfma<<<dim3(32, BB, 3), 256, 0, stream>>>(act0, A, W3, enc_b, sel, 0, 0, 0,  ts);
        conv3x3_mfma<<<dim3(32, BB, 3), 256, 0, stream>>>(A,    B, W3, enc_b, sel, 1, 0, ts, ts);
        conv3x3_mfma<<<dim3(32, BB, 3), 256, 0, stream>>>(B,    A, W3, enc_b, sel, 2, 0, ts, ts);
        conv3x3_mfma<<<dim3(32, BB, 3), 256, 0, stream>>>(A,    B, W3, enc_b, sel, 3, 0, ts, ts);
        decoder_kernel<<<(3 * BB * HH * WW + 255) / 256, 256, 0, stream>>>(
            B, ts, dec_w, dec_b, out, 0, 3);
    } else {
        _Float16* A = bufs;
        _Float16* B = bufs + ACT;
        for (int t = 0; t < TT; ++t) {
            conv3x3_mfma<<<dim3(32, BB, 1), 256, 0, stream>>>(act0, A, W3, enc_b, sel, 0, t, 0, 0);
            conv3x3_mfma<<<dim3(32, BB, 1), 256, 0, stream>>>(A,    B, W3, enc_b, sel, 1, t, 0, 0);
            conv3x3_mfma<<<dim3(32, BB, 1), 256, 0, stream>>>(B,    A, W3, enc_b, sel, 2, t, 0, 0);
            conv3x3_mfma<<<dim3(32, BB, 1), 256, 0, stream>>>(A,    B, W3, enc_b, sel, 3, t, 0, 0);
            decoder_kernel<<<(BB * HH * WW + 255) / 256, 256, 0, stream>>>(
                B, 0, dec_w, dec_b, out, t, 1);
        }
    }
}